// Round 3
// baseline (287.036 us; speedup 1.0000x reference)
//
#include <hip/hip_runtime.h>
#include <cstddef>

#define BATCH   2
#define SEQ     2048
#define DMODEL  1024
#define NH      16
#define HDIM    64
#define WIN     256
#define MTOT    4096

typedef __bf16 bf16;
typedef __attribute__((ext_vector_type(8)))  __bf16 bf16x8;
typedef __attribute__((ext_vector_type(4)))  float  f32x4;
typedef __attribute__((ext_vector_type(16))) float  f32x16;

#define GLOAD_LDS(gp, lp) __builtin_amdgcn_global_load_lds( \
    (const __attribute__((address_space(1))) void*)(gp),    \
    (__attribute__((address_space(3))) void*)(lp), 16, 0, 0)

__device__ __forceinline__ float fast_exp2(float x) {
#if __has_builtin(__builtin_amdgcn_exp2f)
  return __builtin_amdgcn_exp2f(x);
#else
  float r; asm("v_exp_f32 %0, %1" : "=v"(r) : "v"(x)); return r;
#endif
}

// ---------------------------------------------------------------------------
// Merged pre-pass: split x, w1, w2 into bf16 hi/lo in one launch.
// ---------------------------------------------------------------------------
__global__ __launch_bounds__(256)
void cvt_all(const float* __restrict__ x, const float* __restrict__ w1,
             const float* __restrict__ w2, bf16* __restrict__ xh,
             bf16* __restrict__ xl, bf16* __restrict__ w1h,
             bf16* __restrict__ w1l, bf16* __restrict__ w2h,
             bf16* __restrict__ w2l) {
  const int bid = blockIdx.x;
  const float* s; bf16 *hp, *lp; int base;
  if (bid < 2048)      { s = x;  hp = xh;  lp = xl;  base = bid * 2048; }
  else if (bid < 3584) { s = w1; hp = w1h; lp = w1l; base = (bid - 2048) * 2048; }
  else                 { s = w2; hp = w2h; lp = w2l; base = (bid - 3584) * 2048; }
  const int i = base + threadIdx.x * 8;
  float4 a = *(const float4*)(s + i);
  float4 c = *(const float4*)(s + i + 4);
  const float f[8] = {a.x, a.y, a.z, a.w, c.x, c.y, c.z, c.w};
  bf16x8 vh, vl;
#pragma unroll
  for (int j = 0; j < 8; ++j) {
    bf16 hh = (bf16)f[j];
    vh[j] = hh;
    vl[j] = (bf16)(f[j] - (float)hh);
  }
  *(bf16x8*)(hp + i) = vh;
  *(bf16x8*)(lp + i) = vl;
}

// ---------------------------------------------------------------------------
// R10: fused QKV + V^T projection with TYPE-BALANCED block mapping.
// R9 counters (MfmaUtil 19%, VALUBusy 10%, 71% stall) + arithmetic showed
// per-CU imbalance: with 768 blocks = 3/CU round-robin, CU c gets blocks
// {c, c+256, c+512}; type was decided by bid&15 and 256%16==0, so c and
// c+256 always matched -> half the CUs got 2x cross blocks (3 MFMA/acc,
// 2x staging), half got 2x light hh blocks. Fix: bnx = (bid&15) ^
// (((bid>>8)&1)<<3) — bijective per bm-row; same-CU pair now differs in
// type, so every CU gets ~1 cross + 1 hh-K + 1 V^T.
//
// Frag-order K tile layout, 8KB per (b,h,kt): base ((b*16+h)*32+kt)*4096,
//   elem (key,d): ((key>>5)*4+(d>>4))*512 + (((d>>3)&1)*32+(key&31))*8 + (d&7)
// V tile elem (key,d): ((d>>5)*4+((key&63)>>4))*512
//                      + (((key>>3)&1)*32+(d&31))*8 + (key&7)
// ---------------------------------------------------------------------------
__global__ __launch_bounds__(256)
void gemm_qkv_fused(const bf16* __restrict__ xh, const bf16* __restrict__ xl,
                    const bf16* __restrict__ w1h, const bf16* __restrict__ w1l,
                    const float* __restrict__ b1,
                    bf16* __restrict__ Qh, bf16* __restrict__ Ql,
                    bf16* __restrict__ Kt, bf16* __restrict__ Vt) {
  __shared__ bf16 sAh[128 * 32];
  __shared__ bf16 sAl[128 * 32];
  __shared__ bf16 sBh[128 * 32];
  __shared__ bf16 sBl[128 * 32];

  const int t = threadIdx.x, w = t >> 6, lane = t & 63;
  const int ln15 = lane & 15, quad = lane >> 4;
  const int wrow = (w & 1) * 64, wcol = (w >> 1) * 64;
  const int drow = lane >> 2;
  const int dkcol = (lane & 3) * 8;
  const int bid = blockIdx.x;

  f32x4 acc[4][4];
#pragma unroll
  for (int i = 0; i < 4; ++i)
#pragma unroll
    for (int j = 0; j < 4; ++j)
#pragma unroll
      for (int r = 0; r < 4; ++r) acc[i][j][r] = 0.f;

  if (bid < 512) {
    // ---- QKV projection: A = xh/xl [4096][1024], B = w1h/w1l [2048][1024]
    const int bm = (bid >> 4) * 128;
    const int bnx = (bid & 15) ^ (((bid >> 8) & 1) << 3);  // type-balance XOR
    const int bn = bnx * 128;
    const bool cross = (bn < 1024);            // wave-uniform: Q needs hi+lo

    for (int k0 = 0; k0 < DMODEL; k0 += 32) {
      __syncthreads();
#pragma unroll
      for (int half = 0; half < 2; ++half) {
        const int r = w * 32 + half * 16 + drow;
        const size_t goffA = (size_t)(bm + r) * DMODEL + k0 + dkcol;
        const size_t goffB = (size_t)(bn + r) * DMODEL + k0 + dkcol;
        const int loff = (w * 32 + half * 16) * 32;
        GLOAD_LDS(xh + goffA, sAh + loff);
        GLOAD_LDS(w1h + goffB, sBh + loff);
        if (cross) {
          GLOAD_LDS(xl + goffA, sAl + loff);
          GLOAD_LDS(w1l + goffB, sBl + loff);
        }
      }
      __syncthreads();

      bf16x8 afh[4], afl[4], bfh[4], bfl[4];
#pragma unroll
      for (int mt = 0; mt < 4; ++mt) {
        const int off = (wrow + mt * 16 + ln15) * 32 + quad * 8;
        afh[mt] = *(const bf16x8*)&sAh[off];
        if (cross) afl[mt] = *(const bf16x8*)&sAl[off];
      }
#pragma unroll
      for (int nt = 0; nt < 4; ++nt) {
        const int off = (wcol + nt * 16 + ln15) * 32 + quad * 8;
        bfh[nt] = *(const bf16x8*)&sBh[off];
        if (cross) bfl[nt] = *(const bf16x8*)&sBl[off];
      }
#pragma unroll
      for (int mt = 0; mt < 4; ++mt)
#pragma unroll
        for (int nt = 0; nt < 4; ++nt) {
          acc[mt][nt] = __builtin_amdgcn_mfma_f32_16x16x32_bf16(afh[mt], bfh[nt], acc[mt][nt], 0, 0, 0);
          if (cross) {
            acc[mt][nt] = __builtin_amdgcn_mfma_f32_16x16x32_bf16(afh[mt], bfl[nt], acc[mt][nt], 0, 0, 0);
            acc[mt][nt] = __builtin_amdgcn_mfma_f32_16x16x32_bf16(afl[mt], bfh[nt], acc[mt][nt], 0, 0, 0);
          }
        }
    }

    float bbcol[4];
#pragma unroll
    for (int nt = 0; nt < 4; ++nt) bbcol[nt] = b1[bn + wcol + nt * 16 + ln15];

#pragma unroll
    for (int mt = 0; mt < 4; ++mt)
#pragma unroll
      for (int r = 0; r < 4; ++r) {
        const size_t grow = (size_t)(bm + wrow + mt * 16 + quad * 4 + r);
#pragma unroll
        for (int nt = 0; nt < 4; ++nt) {
          const int col = bn + wcol + nt * 16 + ln15;
          const float v = acc[mt][nt][r] + bbcol[nt];
          if (col < 1024) {
            const bf16 hh = (bf16)v;
            Qh[grow * 1024 + col] = hh;
            Ql[grow * 1024 + col] = (bf16)(v - (float)hh);
          } else {
            const int btok = (int)(grow >> 11), key = (int)(grow & 2047);
            const int kt = key >> 6, kw = key & 63;
            const int hh2 = (col - 1024) >> 6, d = col & 63;
            const size_t addr = ((size_t)((btok * 16 + hh2) * 32 + kt) << 12)
                              + (((kw >> 5) * 4 + (d >> 4)) << 9)
                              + ((((d >> 3) & 1) << 5) + (kw & 31)) * 8 + (d & 7);
            Kt[addr] = (bf16)v;
          }
        }
      }
  } else {
    // ---- V^T: A = w1h rows 2048..3071, B = xh [4096][1024], hh-only ----
    const int id = bid - 512;
    const int bm = (id >> 5) * 128, bn = (id & 31) * 128;
    const bf16* Ah = w1h + 2048 * 1024;
    const float* bias = b1 + 2048;

    for (int k0 = 0; k0 < DMODEL; k0 += 32) {
      __syncthreads();
#pragma unroll
      for (int half = 0; half < 2; ++half) {
        const int r = w * 32 + half * 16 + drow;
        const int loff = (w * 32 + half * 16) * 32;
        GLOAD_LDS(Ah + (size_t)(bm + r) * DMODEL + k0 + dkcol, sAh + loff);
        GLOAD_LDS(xh + (size_t)(bn + r) * DMODEL + k0 + dkcol, sBh + loff);
      }
      __syncthreads();

      bf16x8 af[4], bf[4];
#pragma unroll
      for (int mt = 0; mt < 4; ++mt)
        af[mt] = *(const bf16x8*)&sAh[(wrow + mt * 16 + ln15) * 32 + quad * 8];
#pragma unroll
      for (int nt = 0; nt < 4; ++nt)
        bf[nt] = *(const bf16x8*)&sBh[(wcol + nt * 16 + ln15) * 32 + quad * 8];
#pragma unroll
      for (int mt = 0; mt < 4; ++mt)
#pragma unroll
        for (int nt = 0; nt < 4; ++nt)
          acc[mt][nt] = __builtin_amdgcn_mfma_f32_16x16x32_bf16(af[mt], bf[nt], acc[mt][nt], 0, 0, 0);
    }

#pragma unroll
    for (int mt = 0; mt < 4; ++mt)
#pragma unroll
      for (int r = 0; r < 4; ++r) {
        const size_t grow = (size_t)(bm + wrow + mt * 16 + quad * 4 + r);
        const float brow = bias[grow];
        const int hh2 = (int)(grow >> 6), d = (int)(grow & 63);
#pragma unroll
        for (int nt = 0; nt < 4; ++nt) {
          const int col = bn + wcol + nt * 16 + ln15;
          const float v = acc[mt][nt][r] + brow;
          const int btok = col >> 11, key = col & 2047;
          const int kt = key >> 6, kw = key & 63;
          const size_t addr = ((size_t)((btok * 16 + hh2) * 32 + kt) << 12)
                            + (((d >> 5) * 4 + (kw >> 4)) << 9)
                            + ((((kw >> 3) & 1) << 5) + (d & 31)) * 8 + (kw & 7);
          Vt[addr] = (bf16)v;
        }
      }
  }
}

// ---------------------------------------------------------------------------
// R10: out-proj split-K x4 (was x2). Grid (8,32,4) = 1024 blocks = 4/CU,
// K=256 per partial (8 k-steps). atomicAdd into memset-zeroed out; kz=0
// adds bias. fp32 add ordering of 4 partials perturbs the sum by ~1e-5
// absolute — far under the 2.4e-3 bf16-product error floor.
// ---------------------------------------------------------------------------
__global__ __launch_bounds__(256)
void gemm_out_sk(const bf16* __restrict__ Ah, const bf16* __restrict__ Al,
                 const bf16* __restrict__ Bh, const bf16* __restrict__ Bl,
                 const float* __restrict__ bias, float* __restrict__ Cf) {
  __shared__ bf16 sAh[128 * 32];
  __shared__ bf16 sAl[128 * 32];
  __shared__ bf16 sBh[128 * 32];
  __shared__ bf16 sBl[128 * 32];

  const int t = threadIdx.x, w = t >> 6, lane = t & 63;
  const int ln15 = lane & 15, quad = lane >> 4;
  const int bm = blockIdx.y * 128, bn = blockIdx.x * 128;
  const int kz = blockIdx.z;
  const int wrow = (w & 1) * 64, wcol = (w >> 1) * 64;
  const int drow = lane >> 2;
  const int dkcol = (lane & 3) * 8;

  f32x4 acc[4][4];
#pragma unroll
  for (int i = 0; i < 4; ++i)
#pragma unroll
    for (int j = 0; j < 4; ++j)
#pragma unroll
      for (int r = 0; r < 4; ++r) acc[i][j][r] = 0.f;

  const int kbeg = kz * 256, kend = kbeg + 256;
  for (int k0 = kbeg; k0 < kend; k0 += 32) {
    __syncthreads();
#pragma unroll
    for (int half = 0; half < 2; ++half) {
      const int r = w * 32 + half * 16 + drow;
      const size_t goffA = (size_t)(bm + r) * DMODEL + k0 + dkcol;
      const size_t goffB = (size_t)(bn + r) * DMODEL + k0 + dkcol;
      const int loff = (w * 32 + half * 16) * 32;
      GLOAD_LDS(Ah + goffA, sAh + loff);
      GLOAD_LDS(Bh + goffB, sBh + loff);
      GLOAD_LDS(Al + goffA, sAl + loff);
      GLOAD_LDS(Bl + goffB, sBl + loff);
    }
    __syncthreads();

    bf16x8 afh[4], afl[4], bfh[4], bfl[4];
#pragma unroll
    for (int mt = 0; mt < 4; ++mt) {
      const int off = (wrow + mt * 16 + ln15) * 32 + quad * 8;
      afh[mt] = *(const bf16x8*)&sAh[off];
      afl[mt] = *(const bf16x8*)&sAl[off];
    }
#pragma unroll
    for (int nt = 0; nt < 4; ++nt) {
      const int off = (wcol + nt * 16 + ln15) * 32 + quad * 8;
      bfh[nt] = *(const bf16x8*)&sBh[off];
      bfl[nt] = *(const bf16x8*)&sBl[off];
    }
#pragma unroll
    for (int mt = 0; mt < 4; ++mt)
#pragma unroll
      for (int nt = 0; nt < 4; ++nt) {
        acc[mt][nt] = __builtin_amdgcn_mfma_f32_16x16x32_bf16(afh[mt], bfh[nt], acc[mt][nt], 0, 0, 0);
        acc[mt][nt] = __builtin_amdgcn_mfma_f32_16x16x32_bf16(afh[mt], bfl[nt], acc[mt][nt], 0, 0, 0);
        acc[mt][nt] = __builtin_amdgcn_mfma_f32_16x16x32_bf16(afl[mt], bfh[nt], acc[mt][nt], 0, 0, 0);
      }
  }

  float bbcol[4];
#pragma unroll
  for (int nt = 0; nt < 4; ++nt)
    bbcol[nt] = (kz == 0) ? bias[bn + wcol + nt * 16 + ln15] : 0.f;

#pragma unroll
  for (int mt = 0; mt < 4; ++mt)
#pragma unroll
    for (int r = 0; r < 4; ++r) {
      const size_t grow = (size_t)(bm + wrow + mt * 16 + quad * 4 + r);
#pragma unroll
      for (int nt = 0; nt < 4; ++nt) {
        const int col = bn + wcol + nt * 16 + ln15;
        atomicAdd(&Cf[grow * 1024 + col], acc[mt][nt][r] + bbcol[nt]);
      }
    }
}

// ---------------------------------------------------------------------------
// MFMA flash attention — R8: barrier-free 1-wave blocks (unchanged).
// 2048 blocks x 64 thr, no __syncthreads; K/V frags straight from the
// frag-ordered global tiles (1KB bursts, L2-resident). sP wave-private.
// ---------------------------------------------------------------------------
__global__ __launch_bounds__(64, 2)
void attn_mfma(const bf16* __restrict__ Qh, const bf16* __restrict__ Ql,
               const bf16* __restrict__ Kt, const bf16* __restrict__ Vt,
               bf16* __restrict__ Omh, bf16* __restrict__ Oml) {
  const int lane = threadIdx.x & 63;
  const int ln31 = lane & 31, half = lane >> 5;
  const int bid = blockIdx.x;
  const int j = bid & 31;
  const int bh = ((j & 7) << 2) | (j >> 3);    // bid%8 == bh>>2 -> XCD group
  const int c  = 63 - (bid >> 5);              // 32-row q chunk, long-first
  const int b = bh >> 4, h = bh & 15;
  const int i0w = c * 32;                      // this wave's first q row
  const int lim = i0w + WIN;                   // allowed: j <= lim + rl

  __shared__ bf16 sP[32 * 72];                 // wave-private P rows

  // ---- Q fragments: hi+lo combined, scaled by log2(e)/8, re-split ----
  bf16x8 qh[4], ql[4];
  {
    const size_t rowQ = (size_t)(b * SEQ + i0w + ln31);
#pragma unroll
    for (int ks = 0; ks < 4; ++ks) {
      bf16x8 vh = *(const bf16x8*)(Qh + rowQ * 1024 + h * 64 + ks * 16 + half * 8);
      bf16x8 vl = *(const bf16x8*)(Ql + rowQ * 1024 + h * 64 + ks * 16 + half * 8);
#pragma unroll
      for (int jj = 0; jj < 8; ++jj) {
        float f = ((float)vh[jj] + (float)vl[jj]) * 0.1803368801111204f;  // log2(e)/8
        bf16 hh = (bf16)f;
        qh[ks][jj] = hh;
        ql[ks][jj] = (bf16)(f - (float)hh);
      }
    }
  }
  bf16x8 onesf;
#pragma unroll
  for (int jj = 0; jj < 8; ++jj) onesf[jj] = (ln31 == 0) ? (bf16)1.0f : (bf16)0.0f;

  f32x16 accO0, accO1, accL;
#pragma unroll
  for (int r = 0; r < 16; ++r) { accO0[r] = 0.f; accO1[r] = 0.f; accL[r] = 0.f; }

  // per-(b,h) tile bases; each tile is 4096 els, frag-slot ordered
  const bf16* KtBH = Kt + ((size_t)(b * 16 + h) << 17);
  const bf16* VtBH = Vt + ((size_t)(b * 16 + h) << 17);
  const int lane8 = lane * 8;

  const int nkt = min((i0w + 31 + WIN) / 64 + 1, SEQ / 64);

  for (int kt = 0; kt < nkt; ++kt) {
    const bf16* Kb = KtBH + ((size_t)kt << 12);
    const bf16* Vb = VtBH + ((size_t)kt << 12);

    // ---- load all 16 K/V fragments for this tile (1KB bursts, L2-hot).
    // V is loaded up-front so its latency hides under QK^T + softmax. ----
    bf16x8 kf[8], vf[8];
#pragma unroll
    for (int s = 0; s < 8; ++s) {
      kf[s] = *(const bf16x8*)&Kb[(s << 9) + lane8];
      vf[s] = *(const bf16x8*)&Vb[(s << 9) + lane8];
    }

    // ---- S = Q K^T (Q split: hh + lh) ----
    f32x16 S0, S1;
#pragma unroll
    for (int r = 0; r < 16; ++r) { S0[r] = 0.f; S1[r] = 0.f; }
#pragma unroll
    for (int ks = 0; ks < 4; ++ks) {
      S0 = __builtin_amdgcn_mfma_f32_32x32x16_bf16(qh[ks], kf[ks], S0, 0, 0, 0);
      S0 = __builtin_amdgcn_mfma_f32_32x32x16_bf16(ql[ks], kf[ks], S0, 0, 0, 0);
      S1 = __builtin_amdgcn_mfma_f32_32x32x16_bf16(qh[ks], kf[4 + ks], S1, 0, 0, 0);
      S1 = __builtin_amdgcn_mfma_f32_32x32x16_bf16(ql[ks], kf[4 + ks], S1, 0, 0, 0);
    }

    // ---- softmax: p = exp2(s); mask -> 0 after exp; write P to LDS ----
    const int j0 = kt * 64;
#pragma unroll
    for (int cc = 0; cc < 2; ++cc) {
      f32x16& S = cc ? S1 : S0;
      const int vj = j0 + cc * 32 + ln31 - lim;        // mask if vj > rl
      const bool may = (j0 + cc * 32 + 31) > lim;
#pragma unroll
      for (int r = 0; r < 16; ++r) {
        const int rl = (r & 3) + 8 * (r >> 2) + 4 * half;
        float pv = fast_exp2(S[r]);
        if (may && (vj > rl)) pv = 0.f;
        sP[rl * 72 + cc * 32 + ln31] = (bf16)pv;
      }
    }

    // ---- O += P V ; l += P 1  (wave-private P rows; no barrier) ----
#pragma unroll
    for (int ks = 0; ks < 4; ++ks) {
      bf16x8 pA = *(const bf16x8*)&sP[ln31 * 72 + ks * 16 + half * 8];
      accO0 = __builtin_amdgcn_mfma_f32_32x32x16_bf16(pA, vf[ks], accO0, 0, 0, 0);
      accO1 = __builtin_amdgcn_mfma_f32_32x32x16_bf16(pA, vf[4 + ks], accO1, 0, 0, 0);
      accL  = __builtin_amdgcn_mfma_f32_32x32x16_bf16(pA, onesf, accL, 0, 0, 0);
    }
  }

  // ---- epilogue: O /= l, write Om hi/lo ----
#pragma unroll
  for (int r = 0; r < 16; ++r) {
    const int rl = (r & 3) + 8 * (r >> 2) + 4 * half;
    const float lv = __shfl(accL[r], lane & 32, 64);
    const float inv = 1.0f / lv;
    const size_t grow = (size_t)(b * SEQ + i0w + rl);
    const int col0 = h * 64 + ln31;
    const float v0 = accO0[r] * inv;
    const float v1 = accO1[r] * inv;
    const bf16 h0 = (bf16)v0, h1 = (bf16)v1;
    Omh[grow * DMODEL + col0]      = h0;
    Oml[grow * DMODEL + col0]      = (bf16)(v0 - (float)h0);
    Omh[grow * DMODEL + col0 + 32] = h1;
    Oml[grow * DMODEL + col0 + 32] = (bf16)(v1 - (float)h1);
  }
}

// ---------------------------------------------------------------------------
extern "C" void kernel_launch(void* const* d_in, const int* in_sizes, int n_in,
                              void* d_out, int out_size, void* d_ws, size_t ws_size,
                              hipStream_t stream) {
  const float* x  = (const float*)d_in[0];
  const float* w1 = (const float*)d_in[1];
  const float* b1 = (const float*)d_in[2];
  const float* w2 = (const float*)d_in[3];
  const float* b2 = (const float*)d_in[4];
  float* out = (float*)d_out;

  char* ws = (char*)d_ws;
  bf16* Qh   = (bf16*)(ws + 0);          // [4096][1024]
  bf16* Ql   = (bf16*)(ws + 8388608);    // [4096][1024]
  bf16* Kt   = (bf16*)(ws + 16777216);   // frag-order tiles, 8 MB
  bf16* Vt   = (bf16*)(ws + 25165824);   // frag-order tiles, 8 MB
  bf16* xh   = (bf16*)(ws + 33554432);   // [4096][1024]
  bf16* xl   = (bf16*)(ws + 41943040);
  bf16* w1h  = (bf16*)(ws + 50331648);   // [3072][1024]
  bf16* w1l  = (bf16*)(ws + 56623104);
  bf16* w2h  = (bf16*)(ws + 62914560);   // [1024][1024]
  bf16* w2l  = (bf16*)(ws + 65011712);
  bf16* Omh  = xh;                       // reuse (x dead after fused gemm)
  bf16* Oml  = xl;

  // out is accumulated via atomicAdd by the split-K out-proj
  hipMemsetAsync(d_out, 0, (size_t)out_size, stream);

  cvt_all<<<dim3(4096), 256, 0, stream>>>(x, w1, w2, xh, xl, w1h, w1l, w2h, w2l);

  // fused: QKV projection (blocks 0..511, type-balanced) + V^T (512..767)
  gemm_qkv_fused<<<dim3(768), 256, 0, stream>>>(
      xh, xl, w1h, w1l, b1, Qh, Ql, Kt, Vt);

  // barrier-free 1-wave attention: 64 chunks x 32 bh
  attn_mfma<<<dim3(2048), 64, 0, stream>>>(Qh, Ql, Kt, Vt, Omh, Oml);

  // out = Om @ w2^T + b2 (fp32), split-K x4 with atomicAdd epilogue
  gemm_out_sk<<<dim3(DMODEL / 128, MTOT / 128, 4), 256, 0, stream>>>(
      Omh, Oml, w2h, w2l, b2, out);
}

// Round 4
// 251.334 us; speedup vs baseline: 1.1421x; 1.1421x over previous
//
#include <hip/hip_runtime.h>
#include <cstddef>

#define BATCH   2
#define SEQ     2048
#define DMODEL  1024
#define NH      16
#define HDIM    64
#define WIN     256
#define MTOT    4096

typedef __bf16 bf16;
typedef __attribute__((ext_vector_type(8)))  __bf16 bf16x8;
typedef __attribute__((ext_vector_type(4)))  float  f32x4;
typedef __attribute__((ext_vector_type(16))) float  f32x16;

#define GLOAD_LDS(gp, lp) __builtin_amdgcn_global_load_lds( \
    (const __attribute__((address_space(1))) void*)(gp),    \
    (__attribute__((address_space(3))) void*)(lp), 16, 0, 0)

__device__ __forceinline__ float fast_exp2(float x) {
#if __has_builtin(__builtin_amdgcn_exp2f)
  return __builtin_amdgcn_exp2f(x);
#else
  float r; asm("v_exp_f32 %0, %1" : "=v"(r) : "v"(x)); return r;
#endif
}

// ---------------------------------------------------------------------------
// Merged pre-pass: split x, w1, w2 into bf16 hi/lo in one launch.
// ---------------------------------------------------------------------------
__global__ __launch_bounds__(256)
void cvt_all(const float* __restrict__ x, const float* __restrict__ w1,
             const float* __restrict__ w2, bf16* __restrict__ xh,
             bf16* __restrict__ xl, bf16* __restrict__ w1h,
             bf16* __restrict__ w1l, bf16* __restrict__ w2h,
             bf16* __restrict__ w2l) {
  const int bid = blockIdx.x;
  const float* s; bf16 *hp, *lp; int base;
  if (bid < 2048)      { s = x;  hp = xh;  lp = xl;  base = bid * 2048; }
  else if (bid < 3584) { s = w1; hp = w1h; lp = w1l; base = (bid - 2048) * 2048; }
  else                 { s = w2; hp = w2h; lp = w2l; base = (bid - 3584) * 2048; }
  const int i = base + threadIdx.x * 8;
  float4 a = *(const float4*)(s + i);
  float4 c = *(const float4*)(s + i + 4);
  const float f[8] = {a.x, a.y, a.z, a.w, c.x, c.y, c.z, c.w};
  bf16x8 vh, vl;
#pragma unroll
  for (int j = 0; j < 8; ++j) {
    bf16 hh = (bf16)f[j];
    vh[j] = hh;
    vl[j] = (bf16)(f[j] - (float)hh);
  }
  *(bf16x8*)(hp + i) = vh;
  *(bf16x8*)(lp + i) = vl;
}

// ---------------------------------------------------------------------------
// R10: fused QKV + V^T projection with TYPE-BALANCED block mapping.
// (kept: fused kernel dropped out of the top-5 after the balance XOR)
// bnx = (bid&15) ^ (((bid>>8)&1)<<3) — bijective per bm-row; the two
// same-CU round-robin blocks now differ in type (cross vs hh).
//
// Frag-order K tile layout, 8KB per (b,h,kt): base ((b*16+h)*32+kt)*4096,
//   elem (key,d): ((key>>5)*4+(d>>4))*512 + (((d>>3)&1)*32+(key&31))*8 + (d&7)
// V tile elem (key,d): ((d>>5)*4+((key&63)>>4))*512
//                      + (((key>>3)&1)*32+(d&31))*8 + (key&7)
// ---------------------------------------------------------------------------
__global__ __launch_bounds__(256)
void gemm_qkv_fused(const bf16* __restrict__ xh, const bf16* __restrict__ xl,
                    const bf16* __restrict__ w1h, const bf16* __restrict__ w1l,
                    const float* __restrict__ b1,
                    bf16* __restrict__ Qh, bf16* __restrict__ Ql,
                    bf16* __restrict__ Kt, bf16* __restrict__ Vt) {
  __shared__ bf16 sAh[128 * 32];
  __shared__ bf16 sAl[128 * 32];
  __shared__ bf16 sBh[128 * 32];
  __shared__ bf16 sBl[128 * 32];

  const int t = threadIdx.x, w = t >> 6, lane = t & 63;
  const int ln15 = lane & 15, quad = lane >> 4;
  const int wrow = (w & 1) * 64, wcol = (w >> 1) * 64;
  const int drow = lane >> 2;
  const int dkcol = (lane & 3) * 8;
  const int bid = blockIdx.x;

  f32x4 acc[4][4];
#pragma unroll
  for (int i = 0; i < 4; ++i)
#pragma unroll
    for (int j = 0; j < 4; ++j)
#pragma unroll
      for (int r = 0; r < 4; ++r) acc[i][j][r] = 0.f;

  if (bid < 512) {
    // ---- QKV projection: A = xh/xl [4096][1024], B = w1h/w1l [2048][1024]
    const int bm = (bid >> 4) * 128;
    const int bnx = (bid & 15) ^ (((bid >> 8) & 1) << 3);  // type-balance XOR
    const int bn = bnx * 128;
    const bool cross = (bn < 1024);            // wave-uniform: Q needs hi+lo

    for (int k0 = 0; k0 < DMODEL; k0 += 32) {
      __syncthreads();
#pragma unroll
      for (int half = 0; half < 2; ++half) {
        const int r = w * 32 + half * 16 + drow;
        const size_t goffA = (size_t)(bm + r) * DMODEL + k0 + dkcol;
        const size_t goffB = (size_t)(bn + r) * DMODEL + k0 + dkcol;
        const int loff = (w * 32 + half * 16) * 32;
        GLOAD_LDS(xh + goffA, sAh + loff);
        GLOAD_LDS(w1h + goffB, sBh + loff);
        if (cross) {
          GLOAD_LDS(xl + goffA, sAl + loff);
          GLOAD_LDS(w1l + goffB, sBl + loff);
        }
      }
      __syncthreads();

      bf16x8 afh[4], afl[4], bfh[4], bfl[4];
#pragma unroll
      for (int mt = 0; mt < 4; ++mt) {
        const int off = (wrow + mt * 16 + ln15) * 32 + quad * 8;
        afh[mt] = *(const bf16x8*)&sAh[off];
        if (cross) afl[mt] = *(const bf16x8*)&sAl[off];
      }
#pragma unroll
      for (int nt = 0; nt < 4; ++nt) {
        const int off = (wcol + nt * 16 + ln15) * 32 + quad * 8;
        bfh[nt] = *(const bf16x8*)&sBh[off];
        if (cross) bfl[nt] = *(const bf16x8*)&sBl[off];
      }
#pragma unroll
      for (int mt = 0; mt < 4; ++mt)
#pragma unroll
        for (int nt = 0; nt < 4; ++nt) {
          acc[mt][nt] = __builtin_amdgcn_mfma_f32_16x16x32_bf16(afh[mt], bfh[nt], acc[mt][nt], 0, 0, 0);
          if (cross) {
            acc[mt][nt] = __builtin_amdgcn_mfma_f32_16x16x32_bf16(afh[mt], bfl[nt], acc[mt][nt], 0, 0, 0);
            acc[mt][nt] = __builtin_amdgcn_mfma_f32_16x16x32_bf16(afl[mt], bfh[nt], acc[mt][nt], 0, 0, 0);
          }
        }
    }

    float bbcol[4];
#pragma unroll
    for (int nt = 0; nt < 4; ++nt) bbcol[nt] = b1[bn + wcol + nt * 16 + ln15];

#pragma unroll
    for (int mt = 0; mt < 4; ++mt)
#pragma unroll
      for (int r = 0; r < 4; ++r) {
        const size_t grow = (size_t)(bm + wrow + mt * 16 + quad * 4 + r);
#pragma unroll
        for (int nt = 0; nt < 4; ++nt) {
          const int col = bn + wcol + nt * 16 + ln15;
          const float v = acc[mt][nt][r] + bbcol[nt];
          if (col < 1024) {
            const bf16 hh = (bf16)v;
            Qh[grow * 1024 + col] = hh;
            Ql[grow * 1024 + col] = (bf16)(v - (float)hh);
          } else {
            const int btok = (int)(grow >> 11), key = (int)(grow & 2047);
            const int kt = key >> 6, kw = key & 63;
            const int hh2 = (col - 1024) >> 6, d = col & 63;
            const size_t addr = ((size_t)((btok * 16 + hh2) * 32 + kt) << 12)
                              + (((kw >> 5) * 4 + (d >> 4)) << 9)
                              + ((((d >> 3) & 1) << 5) + (kw & 31)) * 8 + (d & 7);
            Kt[addr] = (bf16)v;
          }
        }
      }
  } else {
    // ---- V^T: A = w1h rows 2048..3071, B = xh [4096][1024], hh-only ----
    const int id = bid - 512;
    const int bm = (id >> 5) * 128, bn = (id & 31) * 128;
    const bf16* Ah = w1h + 2048 * 1024;
    const float* bias = b1 + 2048;

    for (int k0 = 0; k0 < DMODEL; k0 += 32) {
      __syncthreads();
#pragma unroll
      for (int half = 0; half < 2; ++half) {
        const int r = w * 32 + half * 16 + drow;
        const int loff = (w * 32 + half * 16) * 32;
        GLOAD_LDS(Ah + (size_t)(bm + r) * DMODEL + k0 + dkcol, sAh + loff);
        GLOAD_LDS(xh + (size_t)(bn + r) * DMODEL + k0 + dkcol, sBh + loff);
      }
      __syncthreads();

      bf16x8 af[4], bf[4];
#pragma unroll
      for (int mt = 0; mt < 4; ++mt)
        af[mt] = *(const bf16x8*)&sAh[(wrow + mt * 16 + ln15) * 32 + quad * 8];
#pragma unroll
      for (int nt = 0; nt < 4; ++nt)
        bf[nt] = *(const bf16x8*)&sBh[(wcol + nt * 16 + ln15) * 32 + quad * 8];
#pragma unroll
      for (int mt = 0; mt < 4; ++mt)
#pragma unroll
        for (int nt = 0; nt < 4; ++nt)
          acc[mt][nt] = __builtin_amdgcn_mfma_f32_16x16x32_bf16(af[mt], bf[nt], acc[mt][nt], 0, 0, 0);
    }

#pragma unroll
    for (int mt = 0; mt < 4; ++mt)
#pragma unroll
      for (int r = 0; r < 4; ++r) {
        const size_t grow = (size_t)(bm + wrow + mt * 16 + quad * 4 + r);
        const float brow = bias[grow];
        const int hh2 = (int)(grow >> 6), d = (int)(grow & 63);
#pragma unroll
        for (int nt = 0; nt < 4; ++nt) {
          const int col = bn + wcol + nt * 16 + ln15;
          const float v = acc[mt][nt][r] + brow;
          const int btok = col >> 11, key = col & 2047;
          const int kt = key >> 6, kw = key & 63;
          const size_t addr = ((size_t)((btok * 16 + hh2) * 32 + kt) << 12)
                            + (((d >> 5) * 4 + (kw >> 4)) << 9)
                            + ((((kw >> 3) & 1) << 5) + (d & 31)) * 8 + (kw & 7);
          Vt[addr] = (bf16)v;
        }
      }
  }
}

// ---------------------------------------------------------------------------
// R11: out-proj as 64x64-tile GEMM, NO split-K, NO atomics.
// R10 post-mortem: atomicAdd split-K x4 wrote 64MB through to HBM
// (device atomics resolve below the non-coherent per-XCD L2s) + ~50MB
// RMW fetch -> 76us atomic-traffic-bound (MfmaUtil 12.6%). Occupancy is
// recovered instead by tile size: grid (16,64) = 1024 blocks = 4/CU,
// full K=1024 per block, plain coalesced stores (16MB written once).
// 4 waves tile 64x64 as 2x2 of 32x32; per k-step each wave DMAs 16 rows
// (1KB) of each buffer; 12 MFMA/k-step/wave. w2 (4MB) is L2-resident,
// A-panel re-reads across the 16 col-tiles absorbed by L3.
// ---------------------------------------------------------------------------
__global__ __launch_bounds__(256)
void gemm_out64(const bf16* __restrict__ Ah, const bf16* __restrict__ Al,
                const bf16* __restrict__ Bh, const bf16* __restrict__ Bl,
                const float* __restrict__ bias, float* __restrict__ Cf) {
  __shared__ bf16 sAh[64 * 32];
  __shared__ bf16 sAl[64 * 32];
  __shared__ bf16 sBh[64 * 32];
  __shared__ bf16 sBl[64 * 32];

  const int t = threadIdx.x, w = t >> 6, lane = t & 63;
  const int ln15 = lane & 15, quad = lane >> 4;
  const int bm = blockIdx.y * 64, bn = blockIdx.x * 64;
  const int wrow = (w & 1) * 32, wcol = (w >> 1) * 32;
  const int drow = lane >> 2;               // 0..15 within wave's 16 rows
  const int dkcol = (lane & 3) * 8;

  f32x4 acc[2][2];
#pragma unroll
  for (int i = 0; i < 2; ++i)
#pragma unroll
    for (int j = 0; j < 2; ++j)
#pragma unroll
      for (int r = 0; r < 4; ++r) acc[i][j][r] = 0.f;

  for (int k0 = 0; k0 < DMODEL; k0 += 32) {
    __syncthreads();
    {
      const int r = w * 16 + drow;          // wave w stages rows w*16..+15
      const size_t goffA = (size_t)(bm + r) * DMODEL + k0 + dkcol;
      const size_t goffB = (size_t)(bn + r) * DMODEL + k0 + dkcol;
      const int loff = (w * 16) * 32;       // 1KB per wave, lane-linear
      GLOAD_LDS(Ah + goffA, sAh + loff);
      GLOAD_LDS(Al + goffA, sAl + loff);
      GLOAD_LDS(Bh + goffB, sBh + loff);
      GLOAD_LDS(Bl + goffB, sBl + loff);
    }
    __syncthreads();

    bf16x8 afh[2], afl[2], bfh[2], bfl[2];
#pragma unroll
    for (int mt = 0; mt < 2; ++mt) {
      const int off = (wrow + mt * 16 + ln15) * 32 + quad * 8;
      afh[mt] = *(const bf16x8*)&sAh[off];
      afl[mt] = *(const bf16x8*)&sAl[off];
    }
#pragma unroll
    for (int nt = 0; nt < 2; ++nt) {
      const int off = (wcol + nt * 16 + ln15) * 32 + quad * 8;
      bfh[nt] = *(const bf16x8*)&sBh[off];
      bfl[nt] = *(const bf16x8*)&sBl[off];
    }
#pragma unroll
    for (int mt = 0; mt < 2; ++mt)
#pragma unroll
      for (int nt = 0; nt < 2; ++nt) {
        acc[mt][nt] = __builtin_amdgcn_mfma_f32_16x16x32_bf16(afh[mt], bfh[nt], acc[mt][nt], 0, 0, 0);
        acc[mt][nt] = __builtin_amdgcn_mfma_f32_16x16x32_bf16(afh[mt], bfl[nt], acc[mt][nt], 0, 0, 0);
        acc[mt][nt] = __builtin_amdgcn_mfma_f32_16x16x32_bf16(afl[mt], bfh[nt], acc[mt][nt], 0, 0, 0);
      }
  }

  float bbcol[2];
#pragma unroll
  for (int nt = 0; nt < 2; ++nt) bbcol[nt] = bias[bn + wcol + nt * 16 + ln15];

#pragma unroll
  for (int mt = 0; mt < 2; ++mt)
#pragma unroll
    for (int r = 0; r < 4; ++r) {
      const size_t grow = (size_t)(bm + wrow + mt * 16 + quad * 4 + r);
#pragma unroll
      for (int nt = 0; nt < 2; ++nt) {
        const int col = bn + wcol + nt * 16 + ln15;
        Cf[grow * 1024 + col] = acc[mt][nt][r] + bbcol[nt];
      }
    }
}

// ---------------------------------------------------------------------------
// MFMA flash attention — R8: barrier-free 1-wave blocks (unchanged).
// 2048 blocks x 64 thr, no __syncthreads; K/V frags straight from the
// frag-ordered global tiles (1KB bursts, L2-resident). sP wave-private.
// ---------------------------------------------------------------------------
__global__ __launch_bounds__(64, 2)
void attn_mfma(const bf16* __restrict__ Qh, const bf16* __restrict__ Ql,
               const bf16* __restrict__ Kt, const bf16* __restrict__ Vt,
               bf16* __restrict__ Omh, bf16* __restrict__ Oml) {
  const int lane = threadIdx.x & 63;
  const int ln31 = lane & 31, half = lane >> 5;
  const int bid = blockIdx.x;
  const int j = bid & 31;
  const int bh = ((j & 7) << 2) | (j >> 3);    // bid%8 == bh>>2 -> XCD group
  const int c  = 63 - (bid >> 5);              // 32-row q chunk, long-first
  const int b = bh >> 4, h = bh & 15;
  const int i0w = c * 32;                      // this wave's first q row
  const int lim = i0w + WIN;                   // allowed: j <= lim + rl

  __shared__ bf16 sP[32 * 72];                 // wave-private P rows

  // ---- Q fragments: hi+lo combined, scaled by log2(e)/8, re-split ----
  bf16x8 qh[4], ql[4];
  {
    const size_t rowQ = (size_t)(b * SEQ + i0w + ln31);
#pragma unroll
    for (int ks = 0; ks < 4; ++ks) {
      bf16x8 vh = *(const bf16x8*)(Qh + rowQ * 1024 + h * 64 + ks * 16 + half * 8);
      bf16x8 vl = *(const bf16x8*)(Ql + rowQ * 1024 + h * 64 + ks * 16 + half * 8);
#pragma unroll
      for (int jj = 0; jj < 8; ++jj) {
        float f = ((float)vh[jj] + (float)vl[jj]) * 0.1803368801111204f;  // log2(e)/8
        bf16 hh = (bf16)f;
        qh[ks][jj] = hh;
        ql[ks][jj] = (bf16)(f - (float)hh);
      }
    }
  }
  bf16x8 onesf;
#pragma unroll
  for (int jj = 0; jj < 8; ++jj) onesf[jj] = (ln31 == 0) ? (bf16)1.0f : (bf16)0.0f;

  f32x16 accO0, accO1, accL;
#pragma unroll
  for (int r = 0; r < 16; ++r) { accO0[r] = 0.f; accO1[r] = 0.f; accL[r] = 0.f; }

  // per-(b,h) tile bases; each tile is 4096 els, frag-slot ordered
  const bf16* KtBH = Kt + ((size_t)(b * 16 + h) << 17);
  const bf16* VtBH = Vt + ((size_t)(b * 16 + h) << 17);
  const int lane8 = lane * 8;

  const int nkt = min((i0w + 31 + WIN) / 64 + 1, SEQ / 64);

  for (int kt = 0; kt < nkt; ++kt) {
    const bf16* Kb = KtBH + ((size_t)kt << 12);
    const bf16* Vb = VtBH + ((size_t)kt << 12);

    // ---- load all 16 K/V fragments for this tile (1KB bursts, L2-hot).
    // V is loaded up-front so its latency hides under QK^T + softmax. ----
    bf16x8 kf[8], vf[8];
#pragma unroll
    for (int s = 0; s < 8; ++s) {
      kf[s] = *(const bf16x8*)&Kb[(s << 9) + lane8];
      vf[s] = *(const bf16x8*)&Vb[(s << 9) + lane8];
    }

    // ---- S = Q K^T (Q split: hh + lh) ----
    f32x16 S0, S1;
#pragma unroll
    for (int r = 0; r < 16; ++r) { S0[r] = 0.f; S1[r] = 0.f; }
#pragma unroll
    for (int ks = 0; ks < 4; ++ks) {
      S0 = __builtin_amdgcn_mfma_f32_32x32x16_bf16(qh[ks], kf[ks], S0, 0, 0, 0);
      S0 = __builtin_amdgcn_mfma_f32_32x32x16_bf16(ql[ks], kf[ks], S0, 0, 0, 0);
      S1 = __builtin_amdgcn_mfma_f32_32x32x16_bf16(qh[ks], kf[4 + ks], S1, 0, 0, 0);
      S1 = __builtin_amdgcn_mfma_f32_32x32x16_bf16(ql[ks], kf[4 + ks], S1, 0, 0, 0);
    }

    // ---- softmax: p = exp2(s); mask -> 0 after exp; write P to LDS ----
    const int j0 = kt * 64;
#pragma unroll
    for (int cc = 0; cc < 2; ++cc) {
      f32x16& S = cc ? S1 : S0;
      const int vj = j0 + cc * 32 + ln31 - lim;        // mask if vj > rl
      const bool may = (j0 + cc * 32 + 31) > lim;
#pragma unroll
      for (int r = 0; r < 16; ++r) {
        const int rl = (r & 3) + 8 * (r >> 2) + 4 * half;
        float pv = fast_exp2(S[r]);
        if (may && (vj > rl)) pv = 0.f;
        sP[rl * 72 + cc * 32 + ln31] = (bf16)pv;
      }
    }

    // ---- O += P V ; l += P 1  (wave-private P rows; no barrier) ----
#pragma unroll
    for (int ks = 0; ks < 4; ++ks) {
      bf16x8 pA = *(const bf16x8*)&sP[ln31 * 72 + ks * 16 + half * 8];
      accO0 = __builtin_amdgcn_mfma_f32_32x32x16_bf16(pA, vf[ks], accO0, 0, 0, 0);
      accO1 = __builtin_amdgcn_mfma_f32_32x32x16_bf16(pA, vf[4 + ks], accO1, 0, 0, 0);
      accL  = __builtin_amdgcn_mfma_f32_32x32x16_bf16(pA, onesf, accL, 0, 0, 0);
    }
  }

  // ---- epilogue: O /= l, write Om hi/lo ----
#pragma unroll
  for (int r = 0; r < 16; ++r) {
    const int rl = (r & 3) + 8 * (r >> 2) + 4 * half;
    const float lv = __shfl(accL[r], lane & 32, 64);
    const float inv = 1.0f / lv;
    const size_t grow = (size_t)(b * SEQ + i0w + rl);
    const int col0 = h * 64 + ln31;
    const float v0 = accO0[r] * inv;
    const float v1 = accO1[r] * inv;
    const bf16 h0 = (bf16)v0, h1 = (bf16)v1;
    Omh[grow * DMODEL + col0]      = h0;
    Oml[grow * DMODEL + col0]      = (bf16)(v0 - (float)h0);
    Omh[grow * DMODEL + col0 + 32] = h1;
    Oml[grow * DMODEL + col0 + 32] = (bf16)(v1 - (float)h1);
  }
}

// ---------------------------------------------------------------------------
extern "C" void kernel_launch(void* const* d_in, const int* in_sizes, int n_in,
                              void* d_out, int out_size, void* d_ws, size_t ws_size,
                              hipStream_t stream) {
  const float* x  = (const float*)d_in[0];
  const float* w1 = (const float*)d_in[1];
  const float* b1 = (const float*)d_in[2];
  const float* w2 = (const float*)d_in[3];
  const float* b2 = (const float*)d_in[4];
  float* out = (float*)d_out;

  char* ws = (char*)d_ws;
  bf16* Qh   = (bf16*)(ws + 0);          // [4096][1024]
  bf16* Ql   = (bf16*)(ws + 8388608);    // [4096][1024]
  bf16* Kt   = (bf16*)(ws + 16777216);   // frag-order tiles, 8 MB
  bf16* Vt   = (bf16*)(ws + 25165824);   // frag-order tiles, 8 MB
  bf16* xh   = (bf16*)(ws + 33554432);   // [4096][1024]
  bf16* xl   = (bf16*)(ws + 41943040);
  bf16* w1h  = (bf16*)(ws + 50331648);   // [3072][1024]
  bf16* w1l  = (bf16*)(ws + 56623104);
  bf16* w2h  = (bf16*)(ws + 62914560);   // [1024][1024]
  bf16* w2l  = (bf16*)(ws + 65011712);
  bf16* Omh  = xh;                       // reuse (x dead after fused gemm)
  bf16* Oml  = xl;

  cvt_all<<<dim3(4096), 256, 0, stream>>>(x, w1, w2, xh, xl, w1h, w1l, w2h, w2l);

  // fused: QKV projection (blocks 0..511, type-balanced) + V^T (512..767)
  gemm_qkv_fused<<<dim3(768), 256, 0, stream>>>(
      xh, xl, w1h, w1l, b1, Qh, Ql, Kt, Vt);

  // barrier-free 1-wave attention: 64 chunks x 32 bh
  attn_mfma<<<dim3(2048), 64, 0, stream>>>(Qh, Ql, Kt, Vt, Omh, Oml);

  // out = Om @ w2^T + b2 (fp32), 64x64 tiles, 1024 blocks, plain stores
  gemm_out64<<<dim3(16, 64), 256, 0, stream>>>(
      Omh, Oml, w2h, w2l, b2, out);
}

// Round 5
// 239.456 us; speedup vs baseline: 1.1987x; 1.0496x over previous
//
#include <hip/hip_runtime.h>
#include <cstddef>

#define BATCH   2
#define SEQ     2048
#define DMODEL  1024
#define NH      16
#define HDIM    64
#define WIN     256
#define MTOT    4096

typedef __bf16 bf16;
typedef __attribute__((ext_vector_type(8)))  __bf16 bf16x8;
typedef __attribute__((ext_vector_type(4)))  float  f32x4;
typedef __attribute__((ext_vector_type(16))) float  f32x16;

#define GLOAD_LDS(gp, lp) __builtin_amdgcn_global_load_lds( \
    (const __attribute__((address_space(1))) void*)(gp),    \
    (__attribute__((address_space(3))) void*)(lp), 16, 0, 0)

__device__ __forceinline__ float fast_exp2(float x) {
#if __has_builtin(__builtin_amdgcn_exp2f)
  return __builtin_amdgcn_exp2f(x);
#else
  float r; asm("v_exp_f32 %0, %1" : "=v"(r) : "v"(x)); return r;
#endif
}

// ---------------------------------------------------------------------------
// Merged pre-pass: split x, w1, w2 into bf16 hi/lo in one launch.
// ---------------------------------------------------------------------------
__global__ __launch_bounds__(256)
void cvt_all(const float* __restrict__ x, const float* __restrict__ w1,
             const float* __restrict__ w2, bf16* __restrict__ xh,
             bf16* __restrict__ xl, bf16* __restrict__ w1h,
             bf16* __restrict__ w1l, bf16* __restrict__ w2h,
             bf16* __restrict__ w2l) {
  const int bid = blockIdx.x;
  const float* s; bf16 *hp, *lp; int base;
  if (bid < 2048)      { s = x;  hp = xh;  lp = xl;  base = bid * 2048; }
  else if (bid < 3584) { s = w1; hp = w1h; lp = w1l; base = (bid - 2048) * 2048; }
  else                 { s = w2; hp = w2h; lp = w2l; base = (bid - 3584) * 2048; }
  const int i = base + threadIdx.x * 8;
  float4 a = *(const float4*)(s + i);
  float4 c = *(const float4*)(s + i + 4);
  const float f[8] = {a.x, a.y, a.z, a.w, c.x, c.y, c.z, c.w};
  bf16x8 vh, vl;
#pragma unroll
  for (int j = 0; j < 8; ++j) {
    bf16 hh = (bf16)f[j];
    vh[j] = hh;
    vl[j] = (bf16)(f[j] - (float)hh);
  }
  *(bf16x8*)(hp + i) = vh;
  *(bf16x8*)(lp + i) = vl;
}

// ---------------------------------------------------------------------------
// R12: fused QKV + V^T with UNIFORM per-CU work.
// R11 post-mortem: 768 blocks = 3/CU, 1 heavy (cross, 3xMFMA/2xstaging)
// + 2 light per CU -> lights drain early, CU tails on one 4-wave block
// (Occupancy 16.5% vs 37.5% static; MfmaUtil 22%). Fix: Q region as
// 128x64 tiles (512 blocks, 24 MFMA + 24KB staging /k-step ~= 1.5x
// light), K 128x128 (256 blocks), V^T 128x128 (256 blocks). 1024 blocks
// = 4/CU; 256 stride => CU c gets {c,c+256,c+512,c+768} = 2Q+1K+1V:
// per-CU MFMA (80/k-step) and staging (80KB/k-step) exactly uniform.
// LDS 28KB/block (112KB/CU), launch_bounds(256,4) pins VGPR<=128 so
// all 16 waves/CU stay resident.
//
// Frag-order K tile layout, 8KB per (b,h,kt): base ((b*16+h)*32+kt)*4096,
//   elem (key,d): ((key>>5)*4+(d>>4))*512 + (((d>>3)&1)*32+(key&31))*8 + (d&7)
// V tile elem (key,d): ((d>>5)*4+((key&63)>>4))*512
//                      + (((key>>3)&1)*32+(d&31))*8 + (key&7)
// ---------------------------------------------------------------------------
__global__ __launch_bounds__(256, 4)
void gemm_qkv_fused(const bf16* __restrict__ xh, const bf16* __restrict__ xl,
                    const bf16* __restrict__ w1h, const bf16* __restrict__ w1l,
                    const float* __restrict__ b1,
                    bf16* __restrict__ Qh, bf16* __restrict__ Ql,
                    bf16* __restrict__ Kt, bf16* __restrict__ Vt) {
  __shared__ bf16 sAh[128 * 32];
  __shared__ bf16 sAl[128 * 32];
  __shared__ bf16 sBh[128 * 32];
  __shared__ bf16 sBl[64 * 32];

  const int t = threadIdx.x, w = t >> 6, lane = t & 63;
  const int ln15 = lane & 15, quad = lane >> 4;
  const int drow = lane >> 2;
  const int dkcol = (lane & 3) * 8;
  const int bid = blockIdx.x;

  if (bid < 512) {
    // ---- Q: 128x64 tile, hi/lo cross (3 MFMA). Wave w owns rows w*32..+31.
    const int bm = (bid >> 4) * 128;
    const int bn = (bid & 15) * 64;

    f32x4 acc[2][4];
#pragma unroll
    for (int i = 0; i < 2; ++i)
#pragma unroll
      for (int j = 0; j < 4; ++j)
#pragma unroll
        for (int r = 0; r < 4; ++r) acc[i][j][r] = 0.f;

    for (int k0 = 0; k0 < DMODEL; k0 += 32) {
      __syncthreads();
#pragma unroll
      for (int half = 0; half < 2; ++half) {
        const int r = w * 32 + half * 16 + drow;
        const size_t goffA = (size_t)(bm + r) * DMODEL + k0 + dkcol;
        const int loff = (w * 32 + half * 16) * 32;
        GLOAD_LDS(xh + goffA, sAh + loff);
        GLOAD_LDS(xl + goffA, sAl + loff);
      }
      {
        const int r = w * 16 + drow;
        const size_t goffB = (size_t)(bn + r) * DMODEL + k0 + dkcol;
        const int loff = (w * 16) * 32;
        GLOAD_LDS(w1h + goffB, sBh + loff);
        GLOAD_LDS(w1l + goffB, sBl + loff);
      }
      __syncthreads();

      bf16x8 afh[2], afl[2], bfh[4], bfl[4];
#pragma unroll
      for (int mt = 0; mt < 2; ++mt) {
        const int off = (w * 32 + mt * 16 + ln15) * 32 + quad * 8;
        afh[mt] = *(const bf16x8*)&sAh[off];
        afl[mt] = *(const bf16x8*)&sAl[off];
      }
#pragma unroll
      for (int nt = 0; nt < 4; ++nt) {
        const int off = (nt * 16 + ln15) * 32 + quad * 8;
        bfh[nt] = *(const bf16x8*)&sBh[off];
        bfl[nt] = *(const bf16x8*)&sBl[off];
      }
#pragma unroll
      for (int mt = 0; mt < 2; ++mt)
#pragma unroll
        for (int nt = 0; nt < 4; ++nt) {
          acc[mt][nt] = __builtin_amdgcn_mfma_f32_16x16x32_bf16(afh[mt], bfh[nt], acc[mt][nt], 0, 0, 0);
          acc[mt][nt] = __builtin_amdgcn_mfma_f32_16x16x32_bf16(afh[mt], bfl[nt], acc[mt][nt], 0, 0, 0);
          acc[mt][nt] = __builtin_amdgcn_mfma_f32_16x16x32_bf16(afl[mt], bfh[nt], acc[mt][nt], 0, 0, 0);
        }
    }

    float bbcol[4];
#pragma unroll
    for (int nt = 0; nt < 4; ++nt) bbcol[nt] = b1[bn + nt * 16 + ln15];

#pragma unroll
    for (int mt = 0; mt < 2; ++mt)
#pragma unroll
      for (int r = 0; r < 4; ++r) {
        const size_t grow = (size_t)(bm + w * 32 + mt * 16 + quad * 4 + r);
#pragma unroll
        for (int nt = 0; nt < 4; ++nt) {
          const int col = bn + nt * 16 + ln15;
          const float v = acc[mt][nt][r] + bbcol[nt];
          const bf16 hh = (bf16)v;
          Qh[grow * 1024 + col] = hh;
          Ql[grow * 1024 + col] = (bf16)(v - (float)hh);
        }
      }
  } else if (bid < 768) {
    // ---- K: 128x128 hh-only -> Kt frag-order tiles ----
    const int kid = bid - 512;
    const int bm = (kid >> 3) * 128, bn = 1024 + (kid & 7) * 128;
    const int wrow = (w & 1) * 64, wcol = (w >> 1) * 64;

    f32x4 acc[4][4];
#pragma unroll
    for (int i = 0; i < 4; ++i)
#pragma unroll
      for (int j = 0; j < 4; ++j)
#pragma unroll
        for (int r = 0; r < 4; ++r) acc[i][j][r] = 0.f;

    for (int k0 = 0; k0 < DMODEL; k0 += 32) {
      __syncthreads();
#pragma unroll
      for (int half = 0; half < 2; ++half) {
        const int r = w * 32 + half * 16 + drow;
        const int loff = (w * 32 + half * 16) * 32;
        GLOAD_LDS(xh + (size_t)(bm + r) * DMODEL + k0 + dkcol, sAh + loff);
        GLOAD_LDS(w1h + (size_t)(bn + r) * DMODEL + k0 + dkcol, sBh + loff);
      }
      __syncthreads();

      bf16x8 af[4], bf[4];
#pragma unroll
      for (int mt = 0; mt < 4; ++mt)
        af[mt] = *(const bf16x8*)&sAh[(wrow + mt * 16 + ln15) * 32 + quad * 8];
#pragma unroll
      for (int nt = 0; nt < 4; ++nt)
        bf[nt] = *(const bf16x8*)&sBh[(wcol + nt * 16 + ln15) * 32 + quad * 8];
#pragma unroll
      for (int mt = 0; mt < 4; ++mt)
#pragma unroll
        for (int nt = 0; nt < 4; ++nt)
          acc[mt][nt] = __builtin_amdgcn_mfma_f32_16x16x32_bf16(af[mt], bf[nt], acc[mt][nt], 0, 0, 0);
    }

    float bbcol[4];
#pragma unroll
    for (int nt = 0; nt < 4; ++nt) bbcol[nt] = b1[bn + wcol + nt * 16 + ln15];

#pragma unroll
    for (int mt = 0; mt < 4; ++mt)
#pragma unroll
      for (int r = 0; r < 4; ++r) {
        const size_t grow = (size_t)(bm + wrow + mt * 16 + quad * 4 + r);
        const int btok = (int)(grow >> 11), key = (int)(grow & 2047);
        const int kt = key >> 6, kw = key & 63;
#pragma unroll
        for (int nt = 0; nt < 4; ++nt) {
          const int col = bn + wcol + nt * 16 + ln15;
          const float v = acc[mt][nt][r] + bbcol[nt];
          const int hh2 = (col - 1024) >> 6, d = col & 63;
          const size_t addr = ((size_t)((btok * 16 + hh2) * 32 + kt) << 12)
                            + (((kw >> 5) * 4 + (d >> 4)) << 9)
                            + ((((d >> 3) & 1) << 5) + (kw & 31)) * 8 + (d & 7);
          Kt[addr] = (bf16)v;
        }
      }
  } else {
    // ---- V^T: A = w1h rows 2048..3071, B = xh, hh-only -> Vt tiles ----
    const int vid = bid - 768;
    const int bm = (vid >> 5) * 128, bn = (vid & 31) * 128;
    const int wrow = (w & 1) * 64, wcol = (w >> 1) * 64;
    const bf16* Ah = w1h + 2048 * 1024;
    const float* bias = b1 + 2048;

    f32x4 acc[4][4];
#pragma unroll
    for (int i = 0; i < 4; ++i)
#pragma unroll
      for (int j = 0; j < 4; ++j)
#pragma unroll
        for (int r = 0; r < 4; ++r) acc[i][j][r] = 0.f;

    for (int k0 = 0; k0 < DMODEL; k0 += 32) {
      __syncthreads();
#pragma unroll
      for (int half = 0; half < 2; ++half) {
        const int r = w * 32 + half * 16 + drow;
        const int loff = (w * 32 + half * 16) * 32;
        GLOAD_LDS(Ah + (size_t)(bm + r) * DMODEL + k0 + dkcol, sAh + loff);
        GLOAD_LDS(xh + (size_t)(bn + r) * DMODEL + k0 + dkcol, sBh + loff);
      }
      __syncthreads();

      bf16x8 af[4], bf[4];
#pragma unroll
      for (int mt = 0; mt < 4; ++mt)
        af[mt] = *(const bf16x8*)&sAh[(wrow + mt * 16 + ln15) * 32 + quad * 8];
#pragma unroll
      for (int nt = 0; nt < 4; ++nt)
        bf[nt] = *(const bf16x8*)&sBh[(wcol + nt * 16 + ln15) * 32 + quad * 8];
#pragma unroll
      for (int mt = 0; mt < 4; ++mt)
#pragma unroll
        for (int nt = 0; nt < 4; ++nt)
          acc[mt][nt] = __builtin_amdgcn_mfma_f32_16x16x32_bf16(af[mt], bf[nt], acc[mt][nt], 0, 0, 0);
    }

#pragma unroll
    for (int mt = 0; mt < 4; ++mt)
#pragma unroll
      for (int r = 0; r < 4; ++r) {
        const size_t grow = (size_t)(bm + wrow + mt * 16 + quad * 4 + r);
        const float brow = bias[grow];
        const int hh2 = (int)(grow >> 6), d = (int)(grow & 63);
#pragma unroll
        for (int nt = 0; nt < 4; ++nt) {
          const int col = bn + wcol + nt * 16 + ln15;
          const float v = acc[mt][nt][r] + brow;
          const int btok = col >> 11, key = col & 2047;
          const int kt = key >> 6, kw = key & 63;
          const size_t addr = ((size_t)((btok * 16 + hh2) * 32 + kt) << 12)
                            + (((d >> 5) * 4 + (kw >> 4)) << 9)
                            + ((((kw >> 3) & 1) << 5) + (d & 31)) * 8 + (kw & 7);
          Vt[addr] = (bf16)v;
        }
      }
  }
}

// ---------------------------------------------------------------------------
// R11: out-proj as 64x64-tile GEMM, NO split-K, NO atomics (unchanged).
// Grid (16,64) = 1024 blocks = 4/CU, full K per block, plain stores.
// ---------------------------------------------------------------------------
__global__ __launch_bounds__(256)
void gemm_out64(const bf16* __restrict__ Ah, const bf16* __restrict__ Al,
                const bf16* __restrict__ Bh, const bf16* __restrict__ Bl,
                const float* __restrict__ bias, float* __restrict__ Cf) {
  __shared__ bf16 sAh[64 * 32];
  __shared__ bf16 sAl[64 * 32];
  __shared__ bf16 sBh[64 * 32];
  __shared__ bf16 sBl[64 * 32];

  const int t = threadIdx.x, w = t >> 6, lane = t & 63;
  const int ln15 = lane & 15, quad = lane >> 4;
  const int bm = blockIdx.y * 64, bn = blockIdx.x * 64;
  const int wrow = (w & 1) * 32, wcol = (w >> 1) * 32;
  const int drow = lane >> 2;
  const int dkcol = (lane & 3) * 8;

  f32x4 acc[2][2];
#pragma unroll
  for (int i = 0; i < 2; ++i)
#pragma unroll
    for (int j = 0; j < 2; ++j)
#pragma unroll
      for (int r = 0; r < 4; ++r) acc[i][j][r] = 0.f;

  for (int k0 = 0; k0 < DMODEL; k0 += 32) {
    __syncthreads();
    {
      const int r = w * 16 + drow;
      const size_t goffA = (size_t)(bm + r) * DMODEL + k0 + dkcol;
      const size_t goffB = (size_t)(bn + r) * DMODEL + k0 + dkcol;
      const int loff = (w * 16) * 32;
      GLOAD_LDS(Ah + goffA, sAh + loff);
      GLOAD_LDS(Al + goffA, sAl + loff);
      GLOAD_LDS(Bh + goffB, sBh + loff);
      GLOAD_LDS(Bl + goffB, sBl + loff);
    }
    __syncthreads();

    bf16x8 afh[2], afl[2], bfh[2], bfl[2];
#pragma unroll
    for (int mt = 0; mt < 2; ++mt) {
      const int off = (wrow + mt * 16 + ln15) * 32 + quad * 8;
      afh[mt] = *(const bf16x8*)&sAh[off];
      afl[mt] = *(const bf16x8*)&sAl[off];
    }
#pragma unroll
    for (int nt = 0; nt < 2; ++nt) {
      const int off = (wcol + nt * 16 + ln15) * 32 + quad * 8;
      bfh[nt] = *(const bf16x8*)&sBh[off];
      bfl[nt] = *(const bf16x8*)&sBl[off];
    }
#pragma unroll
    for (int mt = 0; mt < 2; ++mt)
#pragma unroll
      for (int nt = 0; nt < 2; ++nt) {
        acc[mt][nt] = __builtin_amdgcn_mfma_f32_16x16x32_bf16(afh[mt], bfh[nt], acc[mt][nt], 0, 0, 0);
        acc[mt][nt] = __builtin_amdgcn_mfma_f32_16x16x32_bf16(afh[mt], bfl[nt], acc[mt][nt], 0, 0, 0);
        acc[mt][nt] = __builtin_amdgcn_mfma_f32_16x16x32_bf16(afl[mt], bfh[nt], acc[mt][nt], 0, 0, 0);
      }
  }

  float bbcol[2];
#pragma unroll
  for (int nt = 0; nt < 2; ++nt) bbcol[nt] = bias[bn + wcol + nt * 16 + ln15];

#pragma unroll
  for (int mt = 0; mt < 2; ++mt)
#pragma unroll
    for (int r = 0; r < 4; ++r) {
      const size_t grow = (size_t)(bm + wrow + mt * 16 + quad * 4 + r);
#pragma unroll
      for (int nt = 0; nt < 2; ++nt) {
        const int col = bn + wcol + nt * 16 + ln15;
        Cf[grow * 1024 + col] = acc[mt][nt][r] + bbcol[nt];
      }
    }
}

// ---------------------------------------------------------------------------
// MFMA flash attention — R8: barrier-free 1-wave blocks (unchanged).
// 2048 blocks x 64 thr, no __syncthreads; K/V frags straight from the
// frag-ordered global tiles (1KB bursts, L2-resident). sP wave-private.
// ---------------------------------------------------------------------------
__global__ __launch_bounds__(64, 2)
void attn_mfma(const bf16* __restrict__ Qh, const bf16* __restrict__ Ql,
               const bf16* __restrict__ Kt, const bf16* __restrict__ Vt,
               bf16* __restrict__ Omh, bf16* __restrict__ Oml) {
  const int lane = threadIdx.x & 63;
  const int ln31 = lane & 31, half = lane >> 5;
  const int bid = blockIdx.x;
  const int j = bid & 31;
  const int bh = ((j & 7) << 2) | (j >> 3);    // bid%8 == bh>>2 -> XCD group
  const int c  = 63 - (bid >> 5);              // 32-row q chunk, long-first
  const int b = bh >> 4, h = bh & 15;
  const int i0w = c * 32;                      // this wave's first q row
  const int lim = i0w + WIN;                   // allowed: j <= lim + rl

  __shared__ bf16 sP[32 * 72];                 // wave-private P rows

  // ---- Q fragments: hi+lo combined, scaled by log2(e)/8, re-split ----
  bf16x8 qh[4], ql[4];
  {
    const size_t rowQ = (size_t)(b * SEQ + i0w + ln31);
#pragma unroll
    for (int ks = 0; ks < 4; ++ks) {
      bf16x8 vh = *(const bf16x8*)(Qh + rowQ * 1024 + h * 64 + ks * 16 + half * 8);
      bf16x8 vl = *(const bf16x8*)(Ql + rowQ * 1024 + h * 64 + ks * 16 + half * 8);
#pragma unroll
      for (int jj = 0; jj < 8; ++jj) {
        float f = ((float)vh[jj] + (float)vl[jj]) * 0.1803368801111204f;  // log2(e)/8
        bf16 hh = (bf16)f;
        qh[ks][jj] = hh;
        ql[ks][jj] = (bf16)(f - (float)hh);
      }
    }
  }
  bf16x8 onesf;
#pragma unroll
  for (int jj = 0; jj < 8; ++jj) onesf[jj] = (ln31 == 0) ? (bf16)1.0f : (bf16)0.0f;

  f32x16 accO0, accO1, accL;
#pragma unroll
  for (int r = 0; r < 16; ++r) { accO0[r] = 0.f; accO1[r] = 0.f; accL[r] = 0.f; }

  // per-(b,h) tile bases; each tile is 4096 els, frag-slot ordered
  const bf16* KtBH = Kt + ((size_t)(b * 16 + h) << 17);
  const bf16* VtBH = Vt + ((size_t)(b * 16 + h) << 17);
  const int lane8 = lane * 8;

  const int nkt = min((i0w + 31 + WIN) / 64 + 1, SEQ / 64);

  for (int kt = 0; kt < nkt; ++kt) {
    const bf16* Kb = KtBH + ((size_t)kt << 12);
    const bf16* Vb = VtBH + ((size_t)kt << 12);

    // ---- load all 16 K/V fragments for this tile (1KB bursts, L2-hot).
    // V is loaded up-front so its latency hides under QK^T + softmax. ----
    bf16x8 kf[8], vf[8];
#pragma unroll
    for (int s = 0; s < 8; ++s) {
      kf[s] = *(const bf16x8*)&Kb[(s << 9) + lane8];
      vf[s] = *(const bf16x8*)&Vb[(s << 9) + lane8];
    }

    // ---- S = Q K^T (Q split: hh + lh) ----
    f32x16 S0, S1;
#pragma unroll
    for (int r = 0; r < 16; ++r) { S0[r] = 0.f; S1[r] = 0.f; }
#pragma unroll
    for (int ks = 0; ks < 4; ++ks) {
      S0 = __builtin_amdgcn_mfma_f32_32x32x16_bf16(qh[ks], kf[ks], S0, 0, 0, 0);
      S0 = __builtin_amdgcn_mfma_f32_32x32x16_bf16(ql[ks], kf[ks], S0, 0, 0, 0);
      S1 = __builtin_amdgcn_mfma_f32_32x32x16_bf16(qh[ks], kf[4 + ks], S1, 0, 0, 0);
      S1 = __builtin_amdgcn_mfma_f32_32x32x16_bf16(ql[ks], kf[4 + ks], S1, 0, 0, 0);
    }

    // ---- softmax: p = exp2(s); mask -> 0 after exp; write P to LDS ----
    const int j0 = kt * 64;
#pragma unroll
    for (int cc = 0; cc < 2; ++cc) {
      f32x16& S = cc ? S1 : S0;
      const int vj = j0 + cc * 32 + ln31 - lim;        // mask if vj > rl
      const bool may = (j0 + cc * 32 + 31) > lim;
#pragma unroll
      for (int r = 0; r < 16; ++r) {
        const int rl = (r & 3) + 8 * (r >> 2) + 4 * half;
        float pv = fast_exp2(S[r]);
        if (may && (vj > rl)) pv = 0.f;
        sP[rl * 72 + cc * 32 + ln31] = (bf16)pv;
      }
    }

    // ---- O += P V ; l += P 1  (wave-private P rows; no barrier) ----
#pragma unroll
    for (int ks = 0; ks < 4; ++ks) {
      bf16x8 pA = *(const bf16x8*)&sP[ln31 * 72 + ks * 16 + half * 8];
      accO0 = __builtin_amdgcn_mfma_f32_32x32x16_bf16(pA, vf[ks], accO0, 0, 0, 0);
      accO1 = __builtin_amdgcn_mfma_f32_32x32x16_bf16(pA, vf[4 + ks], accO1, 0, 0, 0);
      accL  = __builtin_amdgcn_mfma_f32_32x32x16_bf16(pA, onesf, accL, 0, 0, 0);
    }
  }

  // ---- epilogue: O /= l, write Om hi/lo ----
#pragma unroll
  for (int r = 0; r < 16; ++r) {
    const int rl = (r & 3) + 8 * (r >> 2) + 4 * half;
    const float lv = __shfl(accL[r], lane & 32, 64);
    const float inv = 1.0f / lv;
    const size_t grow = (size_t)(b * SEQ + i0w + rl);
    const int col0 = h * 64 + ln31;
    const float v0 = accO0[r] * inv;
    const float v1 = accO1[r] * inv;
    const bf16 h0 = (bf16)v0, h1 = (bf16)v1;
    Omh[grow * DMODEL + col0]      = h0;
    Oml[grow * DMODEL + col0]      = (bf16)(v0 - (float)h0);
    Omh[grow * DMODEL + col0 + 32] = h1;
    Oml[grow * DMODEL + col0 + 32] = (bf16)(v1 - (float)h1);
  }
}

// ---------------------------------------------------------------------------
extern "C" void kernel_launch(void* const* d_in, const int* in_sizes, int n_in,
                              void* d_out, int out_size, void* d_ws, size_t ws_size,
                              hipStream_t stream) {
  const float* x  = (const float*)d_in[0];
  const float* w1 = (const float*)d_in[1];
  const float* b1 = (const float*)d_in[2];
  const float* w2 = (const float*)d_in[3];
  const float* b2 = (const float*)d_in[4];
  float* out = (float*)d_out;

  char* ws = (char*)d_ws;
  bf16* Qh   = (bf16*)(ws + 0);          // [4096][1024]
  bf16* Ql   = (bf16*)(ws + 8388608);    // [4096][1024]
  bf16* Kt   = (bf16*)(ws + 16777216);   // frag-order tiles, 8 MB
  bf16* Vt   = (bf16*)(ws + 25165824);   // frag-order tiles, 8 MB
  bf16* xh   = (bf16*)(ws + 33554432);   // [4096][1024]
  bf16* xl   = (bf16*)(ws + 41943040);
  bf16* w1h  = (bf16*)(ws + 50331648);   // [3072][1024]
  bf16* w1l  = (bf16*)(ws + 56623104);
  bf16* w2h  = (bf16*)(ws + 62914560);   // [1024][1024]
  bf16* w2l  = (bf16*)(ws + 65011712);
  bf16* Omh  = xh;                       // reuse (x dead after fused gemm)
  bf16* Oml  = xl;

  cvt_all<<<dim3(4096), 256, 0, stream>>>(x, w1, w2, xh, xl, w1h, w1l, w2h, w2l);

  // fused: Q 128x64 (0..511) + K 128x128 (512..767) + V^T (768..1023)
  gemm_qkv_fused<<<dim3(1024), 256, 0, stream>>>(
      xh, xl, w1h, w1l, b1, Qh, Ql, Kt, Vt);

  // barrier-free 1-wave attention: 64 chunks x 32 bh
  attn_mfma<<<dim3(2048), 64, 0, stream>>>(Qh, Ql, Kt, Vt, Omh, Oml);

  // out = Om @ w2^T + b2 (fp32), 64x64 tiles, 1024 blocks, plain stores
  gemm_out64<<<dim3(16, 64), 256, 0, stream>>>(
      Omh, Oml, w2h, w2l, b2, out);
}